// Round 9
// baseline (264.663 us; speedup 1.0000x reference)
//
#include <hip/hip_runtime.h>

#define NCLUST 256      // clusters 1..256 (cluster 0 = CLID_UNMATCHED, excluded)
#define NFEAT  64
#define NBLK_A 256      // 1 block/CU
#define BIGF   1e30f

#define SUM_SCALE_F  1073741824.0f   // 2^30 (f32 mul by pow2 = exact)
#define SSQ_SCALE_F  16777216.0f     // 2^24
#define INV_SUM_SCALE (1.0 / 1073741824.0)
#define INV_SSQ_SCALE (1.0 / 16777216.0)

typedef __attribute__((ext_vector_type(8))) short  short8v;   // 8 x bf16
typedef __attribute__((ext_vector_type(4))) float  float4v;
typedef unsigned long long u64;

// ---- static device scratch (rewritten fully every call) ----
// fixed-point integer partials: order-free exact sums
__device__ __align__(16) u64      g_psum[(size_t)NCLUST * NBLK_A * NFEAT]; // [c][b][f] 33.5MB
__device__ __align__(16) u64      g_pssq[(size_t)NCLUST * NBLK_A * 8];     // [c][b][8]
__device__ unsigned g_pcnt[NCLUST * NBLK_A * 8];                           // [c][b][8]
__device__ float  g_cnt[NCLUST];
__device__ __align__(16) double g_means64[NCLUST * NFEAT];
__device__ __align__(16) double g_means64T[NFEAT * NCLUST];   // transposed [f][c]
__device__ __align__(16) float  g_means32[NCLUST * NFEAT];
__device__ __align__(16) unsigned short g_tmplbf[NCLUST * NFEAT]; // swizzled bf16 templates
__device__ double g_tn64[NCLUST];
__device__ double g_std64[NCLUST];
__device__ float  g_std32[NCLUST];
__device__ float2 g_ktab[NCLUST];         // (tn_f32, thr2_f32 or -1 if invalid)
__device__ int    g_valid[NCLUST];
__device__ int    g_list[1000000];
__device__ int    g_nlist;

static __device__ __forceinline__ unsigned short f2bf(float x) {
    union { float f; unsigned u; } v; v.f = x;
    unsigned r = v.u + 0x7fffu + ((v.u >> 16) & 1u);   // RNE
    return (unsigned short)(r >> 16);
}

// ---------------- A: segment sums via NATIVE u64 LDS atomics (fixed-point) ----------------
// R8 post-mortem fixes: (1) ssq atomic was 8 lanes -> SAME address (8x RMW
// serialization per spike); now 3-level 8-lane shfl_xor pre-reduce (independent
// across the 8-spike batch, pipelined) + ONE atomic per 8 lanes to distinct
// banks. (2) f64 convert path -> f32: sum addend bit-identical (pow2 mul is an
// exact exponent shift; llrintf rounds the same real), ssq delta ~1e-7 rel,
// far below all decision margins (mask margin ~4.0).
__global__ __launch_bounds__(1024, 4) void kstats(const float* __restrict__ spikes,
                                                  const int* __restrict__ sidx, int n) {
    __shared__ u64      lsum[NCLUST * NFEAT]; // 128 KiB  (c,f) fixed-point 2^30
    __shared__ u64      lssq[NCLUST * 8];     // 16 KiB   (c, lane>>3) fixed-point 2^24
    __shared__ unsigned lcnt[NCLUST * 8];     // 8 KiB    (c, wave&7)
    for (int idx = threadIdx.x; idx < NCLUST * NFEAT; idx += 1024) lsum[idx] = 0ull;
    for (int idx = threadIdx.x; idx < NCLUST * 8; idx += 1024) { lssq[idx] = 0ull; lcnt[idx] = 0u; }
    __syncthreads();

    const int lane = threadIdx.x & 63;
    const int wave = threadIdx.x >> 6;          // 0..15
    const int per  = (n + gridDim.x - 1) / gridDim.x;
    const int s0   = blockIdx.x * per;
    const int s1   = min(n, s0 + per);

    for (int ib = s0 + wave * 8; ib < s1; ib += 16 * 8) {
        float v[8]; int c[8];
        #pragma unroll
        for (int j = 0; j < 8; ++j) {
            int i  = ib + j;
            int rc = (i < s1) ? i : (s1 - 1);
            v[j] = spikes[(size_t)rc * NFEAT + lane];
            c[j] = (i < s1) ? sidx[i] : 0;
        }
        #pragma unroll
        for (int j = 0; j < 8; ++j) {
            int cj = c[j];
            if (cj != 0) {
                float vf = v[j];
                long long sv = llrintf(vf * SUM_SCALE_F);      // == f64 path bit-exactly
                atomicAdd(&lsum[(cj - 1) * NFEAT + lane], (u64)sv);
                float w = vf * vf;                              // 8-lane group reduce
                w += __shfl_xor(w, 1);
                w += __shfl_xor(w, 2);
                w += __shfl_xor(w, 4);
                if ((lane & 7) == 0) {
                    long long qv = llrintf(w * SSQ_SCALE_F);
                    atomicAdd(&lssq[(cj - 1) * 8 + (lane >> 3)], (u64)qv);
                }
                if (lane == 0) atomicAdd(&lcnt[(cj - 1) * 8 + (wave & 7)], 1u);
            }
        }
    }
    __syncthreads();

    const int b = blockIdx.x;
    for (int idx = threadIdx.x; idx < NCLUST * NFEAT; idx += 1024) {
        int c = idx >> 6, f = idx & 63;
        g_psum[((size_t)c * NBLK_A + b) * NFEAT + f] = lsum[idx];
    }
    for (int idx = threadIdx.x; idx < NCLUST * 8; idx += 1024) {
        int c = idx >> 3, k = idx & 7;
        g_pssq[((size_t)c * NBLK_A + b) * 8 + k] = lssq[idx];
        g_pcnt[(c * NBLK_A + b) * 8 + k]         = lcnt[idx];
    }
}

// ---------------- A2: exact integer reduce -> f64 means / cnt / ssq / tn / std ----------------
__global__ __launch_bounds__(256) void kfinal() {
    const int c = blockIdx.x;                 // cluster c+1
    __shared__ u64 redS[4][NFEAT];
    __shared__ double smean[NFEAT];
    __shared__ double sh_cnt, sh_ssq;
    const int f = threadIdx.x & 63, j = threadIdx.x >> 6;

    u64 acc = 0ull;
    for (int b = j; b < NBLK_A; b += 4)
        acc += g_psum[((size_t)c * NBLK_A + b) * NFEAT + f];   // coalesced: [c][b][f]
    redS[j][f] = acc;

    if (threadIdx.x < 64) {
        u64 sq = 0ull; unsigned cn = 0u;
        for (int e = threadIdx.x; e < NBLK_A * 8; e += 64) {
            sq += g_pssq[(size_t)c * NBLK_A * 8 + e];
            cn += g_pcnt[c * NBLK_A * 8 + e];
        }
        #pragma unroll
        for (int o = 32; o; o >>= 1) {
            sq += __shfl_xor(sq, o);
            cn += __shfl_xor(cn, o);
        }
        if (threadIdx.x == 0) {
            sh_cnt = (double)cn;
            sh_ssq = (double)(long long)sq * INV_SSQ_SCALE;
        }
    }
    __syncthreads();

    if (threadIdx.x < NFEAT) {
        long long tot = (long long)(redS[0][f] + redS[1][f] + redS[2][f] + redS[3][f]);
        double cnt = sh_cnt;
        double mean = (cnt > 0.0) ? ((double)tot * INV_SUM_SCALE) / cnt : 0.0;
        g_means64[c * NFEAT + f]  = mean;
        g_means64T[f * NCLUST + c] = mean;
        g_means32[c * NFEAT + f]  = (float)mean;
        smean[f] = mean;
    }
    __syncthreads();
    if (threadIdx.x == 0) {
        double tn = 0.0;
        for (int q = 0; q < NFEAT; ++q) tn += smean[q] * smean[q];
        double cnt = sh_cnt;
        double var = (cnt > 0.0) ? sh_ssq / cnt - tn : 0.0;
        if (var < 0.0) var = 0.0;
        double sd = sqrt(var);
        g_tn64[c] = tn; g_std64[c] = sd; g_std32[c] = (float)sd;
        g_cnt[c] = (float)cnt;
    }
}

// ---------------- A3: median, validity, thresholds, + bf16 template pre-convert ----------------
__global__ __launch_bounds__(256) void kmedian() {
    __shared__ float svals[NCLUST];
    __shared__ int   svalid[NCLUST];
    __shared__ float mred[2];
    int t = threadIdx.x;
    if (t == 0) { mred[0] = 0.f; mred[1] = 0.f; g_nlist = 0; }  // kzero folded in
    float cnt = g_cnt[t];
    int v0 = (cnt > 0.f) ? 1 : 0;
    float sd = g_std32[t];
    svals[t] = sd; svalid[t] = v0;
    __syncthreads();

    int m = 0, rank = 0;
    for (int jj = 0; jj < NCLUST; ++jj) {
        if (svalid[jj]) {
            ++m;
            float sj = svals[jj];
            if (sj < sd || (sj == sd && jj < t)) ++rank;
        }
    }
    if (v0) {
        if (rank == (m - 1) / 2) mred[0] = sd;
        if (rank == m / 2)       mred[1] = sd;
    }
    __syncthreads();
    float med = 0.5f * (mred[0] + mred[1]);

    int valid = v0 && (sd <= 3.0f * med);
    double sd64 = g_std64[t];
    float thr2 = valid ? (float)((1.5 * sd64) * (1.5 * sd64)) : -1.0f;
    g_valid[t] = valid;
    g_ktab[t]  = make_float2((float)g_tn64[t], thr2);

    // pre-convert templates to bf16 in the SWIZZLED layout (once, not per kmatch block)
    for (int q = threadIdx.x; q < NCLUST * 8; q += 256) {
        int c = q >> 3, g = q & 7;
        float4 u0 = *(const float4*)&g_means32[c * NFEAT + g * 8];
        float4 u1 = *(const float4*)&g_means32[c * NFEAT + g * 8 + 4];
        short8v h;
        h[0] = (short)f2bf(u0.x); h[1] = (short)f2bf(u0.y);
        h[2] = (short)f2bf(u0.z); h[3] = (short)f2bf(u0.w);
        h[4] = (short)f2bf(u1.x); h[5] = (short)f2bf(u1.y);
        h[6] = (short)f2bf(u1.z); h[7] = (short)f2bf(u1.w);
        unsigned byteoff = (unsigned)c * 128u + (((unsigned)g * 16u) ^ (((unsigned)c & 7u) << 4));
        *(short8v*)((char*)g_tmplbf + byteoff) = h;
    }
}

// ---------------- C: MFMA bulk min pass, 256 spikes per block ----------------
// mfma_f32_16x16x32_bf16: A lane l -> row=l&15, k=(l>>4)*8+j ; B lane l -> col=l&15, same k map.
// D lane l, reg r -> row=(l>>4)*4+r, col=l&15  [verified layout, m89]
__global__ __launch_bounds__(256) void kmatch(const float* __restrict__ spikes,
                                              const int* __restrict__ sidx,
                                              const unsigned char* __restrict__ midx,
                                              float* __restrict__ out, int n) {
    __shared__ __align__(16) unsigned short tml[NCLUST * NFEAT]; // 32 KiB swizzled bf16
    __shared__ float2 ktab_sh[NCLUST];

    // stage pre-swizzled templates: linear 16B copies
    for (int idx = threadIdx.x * 8; idx < NCLUST * NFEAT; idx += 256 * 8)
        *(short8v*)&tml[idx] = *(const short8v*)&g_tmplbf[idx];
    if (threadIdx.x < NCLUST) ktab_sh[threadIdx.x] = g_ktab[threadIdx.x];
    __syncthreads();

    const int lane = threadIdx.x & 63, wave = threadIdx.x >> 6;
    const int row  = lane & 15, grp = lane >> 4;
    const int i0w  = blockIdx.x * 256 + wave * 64;   // this wave's 64 spikes

    #pragma unroll 1
    for (int sb = 0; sb < 4; ++sb) {
        const int i0 = i0w + sb * 16;

        // ---- A fragments (spikes straight from global, f32 -> bf16) ----
        int ri = i0 + row;
        int rc = (ri < n) ? ri : (n - 1);
        const float* sp = spikes + (size_t)rc * NFEAT + grp * 8;
        float4 a0 = *(const float4*)(sp);
        float4 a1 = *(const float4*)(sp + 4);
        float4 a2 = *(const float4*)(sp + 32);
        float4 a3 = *(const float4*)(sp + 36);
        short8v af0, af1;
        af0[0] = (short)f2bf(a0.x); af0[1] = (short)f2bf(a0.y);
        af0[2] = (short)f2bf(a0.z); af0[3] = (short)f2bf(a0.w);
        af0[4] = (short)f2bf(a1.x); af0[5] = (short)f2bf(a1.y);
        af0[6] = (short)f2bf(a1.z); af0[7] = (short)f2bf(a1.w);
        af1[0] = (short)f2bf(a2.x); af1[1] = (short)f2bf(a2.y);
        af1[2] = (short)f2bf(a2.z); af1[3] = (short)f2bf(a2.w);
        af1[4] = (short)f2bf(a3.x); af1[5] = (short)f2bf(a3.y);
        af1[6] = (short)f2bf(a3.z); af1[7] = (short)f2bf(a3.w);

        // sn (|s|^2) in f32 from ORIGINAL f32 values; reduce across the 4 k-groups
        float pss = a0.x*a0.x + a0.y*a0.y + a0.z*a0.z + a0.w*a0.w
                  + a1.x*a1.x + a1.y*a1.y + a1.z*a1.z + a1.w*a1.w
                  + a2.x*a2.x + a2.y*a2.y + a2.z*a2.z + a2.w*a2.w
                  + a3.x*a3.x + a3.y*a3.y + a3.z*a3.z + a3.w*a3.w;
        pss += __shfl_xor(pss, 16);
        pss += __shfl_xor(pss, 32);          // now sn of row `row` on every lane

        float snr[4];
        #pragma unroll
        for (int r = 0; r < 4; ++r) snr[r] = __shfl(pss, grp * 4 + r);

        float d2min[4] = {3.4e38f, 3.4e38f, 3.4e38f, 3.4e38f};

        #pragma unroll 2
        for (int nt = 0; nt < 16; ++nt) {
            int c = nt * 16 + row;
            unsigned co = (unsigned)c * 128u;
            unsigned sw = (((unsigned)c & 7u) << 4);
            short8v b0 = *(short8v*)((char*)tml + (co + (((unsigned)grp * 16u) ^ sw)));
            short8v b1 = *(short8v*)((char*)tml + (co + ((((unsigned)grp + 4u) * 16u) ^ sw)));
            float4v acc = {0.f, 0.f, 0.f, 0.f};
            acc = __builtin_amdgcn_mfma_f32_16x16x32_bf16(af0, b0, acc, 0, 0, 0);
            acc = __builtin_amdgcn_mfma_f32_16x16x32_bf16(af1, b1, acc, 0, 0, 0);
            float2 kt = ktab_sh[c];
            #pragma unroll
            for (int r = 0; r < 4; ++r) {
                float d2 = (snr[r] - 2.0f * acc[r]) + kt.x;
                if (!(d2 > kt.y)) d2min[r] = fminf(d2min[r], d2);  // thr2=-1 => masked
            }
        }

        // min over the 16 cluster-lanes (xor 1,2,4,8)
        #pragma unroll
        for (int o = 1; o < 16; o <<= 1) {
            #pragma unroll
            for (int r = 0; r < 4; ++r) d2min[r] = fminf(d2min[r], __shfl_xor(d2min[r], o));
        }
        if (row == 0) {
            #pragma unroll
            for (int r = 0; r < 4; ++r) {
                int i = i0 + grp * 4 + r;
                if (i < n) {
                    float dm = d2min[r];
                    out[2 * (size_t)n + i] = (dm > 1e37f) ? BIGF : sqrtf(fmaxf(dm, 0.f));
                }
            }
        }
    }

    // pass-through outputs + unmatched list (256 threads cover this block's 256 spikes)
    int i = blockIdx.x * 256 + threadIdx.x;
    if (i < n) {
        int si = sidx[i];
        out[i]             = (float)si;
        out[(size_t)n + i] = midx[i] ? 1.0f : 0.0f;
        if (si == 0) {
            int p = atomicAdd(&g_nlist, 1);
            if (p < 1000000) g_list[p] = i;
        }
    }
}

// ---------------- D: precise f64 argmin, LANE = CLUSTER ----------------
__global__ __launch_bounds__(256) void kprecise(const float* __restrict__ spikes,
                                                float* __restrict__ out, int n) {
    const int lane  = threadIdx.x & 63;
    const int gwave = (blockIdx.x * 256 + threadIdx.x) >> 6;
    const int nwave = (gridDim.x * 256) >> 6;
    const int nt    = g_nlist;

    // per-lane cluster constants (c = q*64 + lane), coalesced loads
    double tn[4], thr[4]; int vld[4];
    #pragma unroll
    for (int q = 0; q < 4; ++q) {
        int c = q * 64 + lane;
        tn[q]  = g_tn64[c];
        thr[q] = 1.5 * g_std64[c];
        vld[q] = g_valid[c];
    }

    for (int t = gwave; t < nt; t += nwave) {
        const int i = g_list[t];
        const double sf = (double)spikes[(size_t)i * NFEAT + lane];

        double sn = sf * sf;                 // once per spike
        #pragma unroll
        for (int o = 32; o; o >>= 1) sn += __shfl_xor(sn, o);

        double d0 = 0.0, d1 = 0.0, d2a = 0.0, d3 = 0.0;
        #pragma unroll 16
        for (int f = 0; f < NFEAT; ++f) {
            double b = __shfl(sf, f);        // independent across f
            const double* mrow = &g_means64T[(size_t)f * NCLUST + lane];
            d0 = fma(b, mrow[0],   d0);
            d1 = fma(b, mrow[64],  d1);
            d2a = fma(b, mrow[128], d2a);
            d3 = fma(b, mrow[192], d3);
        }
        double dot[4] = {d0, d1, d2a, d3};

        double dmin = 1e30; int best = 0;
        #pragma unroll
        for (int q = 0; q < 4; ++q) {        // ascending q => ascending cluster id
            if (!vld[q]) continue;
            double d2 = (sn - 2.0 * dot[q]) + tn[q];
            double dist = sqrt(fmax(d2, 0.0));
            if (dist > thr[q]) continue;
            if (dist < dmin) { dmin = dist; best = q * 64 + lane + 1; }
        }

        // cross-lane argmin with first-index tie-break
        #pragma unroll
        for (int o = 32; o; o >>= 1) {
            double od = __shfl_xor(dmin, o);
            int    ob = __shfl_xor(best, o);
            if (od < dmin || (od == dmin && ob < best)) { dmin = od; best = ob; }
        }

        if (dmin >= 256.0) best = 0;   // FIRST_MATCH_MAX_DIST * N_SAMPLES

        if (lane == 0) {
            out[i]                 = (float)best;
            out[(size_t)n + i]     = (best != 0) ? 1.0f : 0.0f;
            out[2 * (size_t)n + i] = (float)dmin;
        }
    }
}

extern "C" void kernel_launch(void* const* d_in, const int* in_sizes, int n_in,
                              void* d_out, int out_size, void* d_ws, size_t ws_size,
                              hipStream_t stream) {
    const float*         spikes = (const float*)d_in[0];
    const int*           sidx   = (const int*)d_in[1];
    const unsigned char* midx   = (const unsigned char*)d_in[2];
    float*               out    = (float*)d_out;
    const int n = in_sizes[1];

    kstats<<<NBLK_A, 1024, 0, stream>>>(spikes, sidx, n);
    kfinal<<<NCLUST, 256, 0, stream>>>();
    kmedian<<<1, 256, 0, stream>>>();
    int nblk = (n + 255) / 256;
    kmatch<<<nblk, 256, 0, stream>>>(spikes, sidx, midx, out, n);
    kprecise<<<1024, 256, 0, stream>>>(spikes, out, n);
}

// Round 10
// 210.545 us; speedup vs baseline: 1.2570x; 1.2570x over previous
//
#include <hip/hip_runtime.h>

#define NCLUST 256      // clusters 1..256 (cluster 0 = CLID_UNMATCHED, excluded)
#define NFEAT  64
#define NBLK_A 256      // 1 block/CU
#define BIGF   1e30f

#define SUMSC  16777216.0f      // 2^24 (pow2 mul = exact exponent shift)
#define SSQSC  2097152.0f       // 2^21
#define INV_SUMSC (1.0 / 16777216.0)
#define INV_SSQSC (1.0 / 2097152.0)

typedef __attribute__((ext_vector_type(8))) short  short8v;   // 8 x bf16
typedef __attribute__((ext_vector_type(4))) float  float4v;
typedef unsigned long long u64;

// ---- static device scratch (rewritten fully every call) ----
// u32 fixed-point partials: order-free exact (mod-2^32 int adds commute; final
// value < 2^31 by >20-sigma margin => signed cast recovers exactly)
__device__ __align__(16) unsigned g_psum[(size_t)NCLUST * NBLK_A * NFEAT]; // 16.7MB
__device__ __align__(16) unsigned g_pssq[(size_t)NCLUST * NBLK_A * NFEAT]; // 16.7MB
__device__ unsigned g_pcnt[NCLUST * NBLK_A * 8];
__device__ float  g_cnt[NCLUST];
__device__ __align__(16) double g_means64[NCLUST * NFEAT];
__device__ __align__(16) double g_means64T[NFEAT * NCLUST];   // transposed [f][c]
__device__ __align__(16) unsigned short g_tmplbf[NCLUST * NFEAT]; // swizzled bf16 templates
__device__ double g_tn64[NCLUST];
__device__ double g_std64[NCLUST];
__device__ float  g_std32[NCLUST];
__device__ float2 g_ktab[NCLUST];         // (tn_f32, thr2_f32 or -1 if invalid)
__device__ int    g_valid[NCLUST];
__device__ int    g_list[1000000];
__device__ int    g_nlist;

static __device__ __forceinline__ unsigned short f2bf(float x) {
    union { float f; unsigned u; } v; v.f = x;
    unsigned r = v.u + 0x7fffu + ((v.u >> 16) & 1u);   // RNE
    return (unsigned short)(r >> 16);
}

// ---------------- A: segment sums, u32 fire-and-forget LDS atomics only ----------------
// R9 lesson: NEVER trade a fire-and-forget atomic for a dependent shuffle chain.
// Lane = feature pair (m=lane&31 -> feats 2m,2m+1); half-wave = spike (half=lane>>5).
// Per 2 spikes: 1 float2 load (512B/wave) + 4 ds_add_u32 + rare cnt atomic. No shuffles.
__global__ __launch_bounds__(1024, 4) void kstats(const float* __restrict__ spikes,
                                                  const int* __restrict__ sidx, int n) {
    __shared__ unsigned lsum[NCLUST * NFEAT]; // 64 KiB  fixed-point 2^24
    __shared__ unsigned lssq[NCLUST * NFEAT]; // 64 KiB  fixed-point 2^21
    __shared__ unsigned lcnt[NCLUST * 8];     // 8 KiB
    for (int idx = threadIdx.x; idx < NCLUST * NFEAT; idx += 1024) { lsum[idx] = 0u; lssq[idx] = 0u; }
    for (int idx = threadIdx.x; idx < NCLUST * 8; idx += 1024) lcnt[idx] = 0u;
    __syncthreads();

    const int lane = threadIdx.x & 63;
    const int wave = threadIdx.x >> 6;          // 0..15
    const int half = lane >> 5;                 // 0/1: which spike of the pair
    const int m    = lane & 31;                 // feature pair index
    const int per  = (n + gridDim.x - 1) / gridDim.x;
    const int s0   = blockIdx.x * per;
    const int s1   = min(n, s0 + per);

    for (int ib = s0 + wave * 16; ib < s1; ib += 16 * 16) {   // 8 pairs = 16 spikes/wave/iter
        float2 v[8]; int cc[8];
        #pragma unroll
        for (int p = 0; p < 8; ++p) {
            int i  = ib + p * 2 + half;
            int rc = (i < s1) ? i : (s1 - 1);
            v[p]  = *(const float2*)(spikes + (size_t)rc * NFEAT + m * 2);
            cc[p] = (i < s1) ? sidx[i] : 0;
        }
        #pragma unroll
        for (int p = 0; p < 8; ++p) {
            int c = cc[p];
            if (c != 0) {                        // per-half predication; atomics exec-masked
                int base = (c - 1) * NFEAT + m * 2;
                atomicAdd(&lsum[base],     (unsigned)__float2int_rn(v[p].x * SUMSC));
                atomicAdd(&lsum[base + 1], (unsigned)__float2int_rn(v[p].y * SUMSC));
                atomicAdd(&lssq[base],     (unsigned)__float2int_rn(v[p].x * v[p].x * SSQSC));
                atomicAdd(&lssq[base + 1], (unsigned)__float2int_rn(v[p].y * v[p].y * SSQSC));
                if (m == 0) atomicAdd(&lcnt[(c - 1) * 8 + (wave & 7)], 1u);
            }
        }
    }
    __syncthreads();

    const int b = blockIdx.x;
    for (int idx = threadIdx.x; idx < NCLUST * NFEAT; idx += 1024) {
        int c = idx >> 6, f = idx & 63;
        g_psum[((size_t)c * NBLK_A + b) * NFEAT + f] = lsum[idx];
        g_pssq[((size_t)c * NBLK_A + b) * NFEAT + f] = lssq[idx];
    }
    for (int idx = threadIdx.x; idx < NCLUST * 8; idx += 1024) {
        int c = idx >> 3, k = idx & 7;
        g_pcnt[(c * NBLK_A + b) * 8 + k] = lcnt[idx];
    }
}

// ---------------- A2: exact integer reduce -> f64 means / tn / std + bf16 templates ----------------
__global__ __launch_bounds__(256) void kfinal() {
    const int c = blockIdx.x;                 // cluster c+1
    __shared__ long long red [4][NFEAT];
    __shared__ long long redq[4][NFEAT];
    __shared__ double smean[NFEAT];
    __shared__ double sh_cnt;
    const int f = threadIdx.x & 63, j = threadIdx.x >> 6;

    long long acc = 0, accq = 0;
    for (int b = j; b < NBLK_A; b += 4) {
        acc  += (int)g_psum[((size_t)c * NBLK_A + b) * NFEAT + f];   // coalesced [c][b][f]
        accq += (int)g_pssq[((size_t)c * NBLK_A + b) * NFEAT + f];
    }
    red[j][f] = acc; redq[j][f] = accq;

    if (threadIdx.x < 64) {
        unsigned cn = 0u;
        for (int e = threadIdx.x; e < NBLK_A * 8; e += 64)
            cn += g_pcnt[c * NBLK_A * 8 + e];
        #pragma unroll
        for (int o = 32; o; o >>= 1) cn += __shfl_xor(cn, o);
        if (threadIdx.x == 0) sh_cnt = (double)cn;
    }
    __syncthreads();

    if (threadIdx.x < NFEAT) {
        long long tot = ((red[0][f] + red[1][f]) + red[2][f]) + red[3][f];
        double cnt = sh_cnt;
        double mean = (cnt > 0.0) ? ((double)tot * INV_SUMSC) / cnt : 0.0;
        g_means64[c * NFEAT + f]   = mean;
        g_means64T[f * NCLUST + c] = mean;
        smean[f] = mean;
        redq[0][f] = ((redq[0][f] + redq[1][f]) + redq[2][f]) + redq[3][f];
        // bf16 template write, swizzled layout (moved out of the serial kmedian)
        unsigned short hb = f2bf((float)mean);
        unsigned g = (unsigned)(f >> 3);
        unsigned byteoff = (unsigned)c * 128u
                         + (((g * 16u) ^ (((unsigned)c & 7u) << 4)) + (unsigned)(f & 7) * 2u);
        *(unsigned short*)((char*)g_tmplbf + byteoff) = hb;
    }
    __syncthreads();
    if (threadIdx.x == 0) {
        double tn = 0.0; long long qs = 0;
        for (int q = 0; q < NFEAT; ++q) { tn += smean[q] * smean[q]; qs += redq[0][q]; }
        double cnt = sh_cnt;
        double var = (cnt > 0.0) ? ((double)qs * INV_SSQSC) / cnt - tn : 0.0;
        if (var < 0.0) var = 0.0;
        double sd = sqrt(var);
        g_tn64[c] = tn; g_std64[c] = sd; g_std32[c] = (float)sd;
        g_cnt[c] = (float)cnt;
    }
}

// ---------------- A3: median, validity, thresholds (tiny serial kernel) ----------------
__global__ __launch_bounds__(256) void kmedian() {
    __shared__ float svals[NCLUST];
    __shared__ int   svalid[NCLUST];
    __shared__ float mred[2];
    int t = threadIdx.x;
    if (t == 0) { mred[0] = 0.f; mred[1] = 0.f; g_nlist = 0; }
    float cnt = g_cnt[t];
    int v0 = (cnt > 0.f) ? 1 : 0;
    float sd = g_std32[t];
    svals[t] = sd; svalid[t] = v0;
    __syncthreads();

    int m = 0, rank = 0;
    for (int jj = 0; jj < NCLUST; ++jj) {
        if (svalid[jj]) {
            ++m;
            float sj = svals[jj];
            if (sj < sd || (sj == sd && jj < t)) ++rank;
        }
    }
    if (v0) {
        if (rank == (m - 1) / 2) mred[0] = sd;
        if (rank == m / 2)       mred[1] = sd;
    }
    __syncthreads();
    float med = 0.5f * (mred[0] + mred[1]);

    int valid = v0 && (sd <= 3.0f * med);
    double sd64 = g_std64[t];
    float thr2 = valid ? (float)((1.5 * sd64) * (1.5 * sd64)) : -1.0f;
    g_valid[t] = valid;
    g_ktab[t]  = make_float2((float)g_tn64[t], thr2);
}

// ---------------- C: MFMA bulk min pass, 256 spikes per block ----------------
// mfma_f32_16x16x32_bf16: A lane l -> row=l&15, k=(l>>4)*8+j ; B lane l -> col=l&15, same k map.
// D lane l, reg r -> row=(l>>4)*4+r, col=l&15  [verified layout, m89]
__global__ __launch_bounds__(256) void kmatch(const float* __restrict__ spikes,
                                              const int* __restrict__ sidx,
                                              const unsigned char* __restrict__ midx,
                                              float* __restrict__ out, int n) {
    __shared__ __align__(16) unsigned short tml[NCLUST * NFEAT]; // 32 KiB swizzled bf16
    __shared__ float2 ktab_sh[NCLUST];

    // stage pre-swizzled templates: linear 16B copies
    for (int idx = threadIdx.x * 8; idx < NCLUST * NFEAT; idx += 256 * 8)
        *(short8v*)&tml[idx] = *(const short8v*)&g_tmplbf[idx];
    if (threadIdx.x < NCLUST) ktab_sh[threadIdx.x] = g_ktab[threadIdx.x];
    __syncthreads();

    const int lane = threadIdx.x & 63, wave = threadIdx.x >> 6;
    const int row  = lane & 15, grp = lane >> 4;
    const int i0w  = blockIdx.x * 256 + wave * 64;   // this wave's 64 spikes

    #pragma unroll 1
    for (int sb = 0; sb < 4; ++sb) {
        const int i0 = i0w + sb * 16;

        // ---- A fragments (spikes straight from global, f32 -> bf16) ----
        int ri = i0 + row;
        int rc = (ri < n) ? ri : (n - 1);
        const float* sp = spikes + (size_t)rc * NFEAT + grp * 8;
        float4 a0 = *(const float4*)(sp);
        float4 a1 = *(const float4*)(sp + 4);
        float4 a2 = *(const float4*)(sp + 32);
        float4 a3 = *(const float4*)(sp + 36);
        short8v af0, af1;
        af0[0] = (short)f2bf(a0.x); af0[1] = (short)f2bf(a0.y);
        af0[2] = (short)f2bf(a0.z); af0[3] = (short)f2bf(a0.w);
        af0[4] = (short)f2bf(a1.x); af0[5] = (short)f2bf(a1.y);
        af0[6] = (short)f2bf(a1.z); af0[7] = (short)f2bf(a1.w);
        af1[0] = (short)f2bf(a2.x); af1[1] = (short)f2bf(a2.y);
        af1[2] = (short)f2bf(a2.z); af1[3] = (short)f2bf(a2.w);
        af1[4] = (short)f2bf(a3.x); af1[5] = (short)f2bf(a3.y);
        af1[6] = (short)f2bf(a3.z); af1[7] = (short)f2bf(a3.w);

        // sn (|s|^2) in f32 from ORIGINAL f32 values; reduce across the 4 k-groups
        float pss = a0.x*a0.x + a0.y*a0.y + a0.z*a0.z + a0.w*a0.w
                  + a1.x*a1.x + a1.y*a1.y + a1.z*a1.z + a1.w*a1.w
                  + a2.x*a2.x + a2.y*a2.y + a2.z*a2.z + a2.w*a2.w
                  + a3.x*a3.x + a3.y*a3.y + a3.z*a3.z + a3.w*a3.w;
        pss += __shfl_xor(pss, 16);
        pss += __shfl_xor(pss, 32);          // now sn of row `row` on every lane

        float snr[4];
        #pragma unroll
        for (int r = 0; r < 4; ++r) snr[r] = __shfl(pss, grp * 4 + r);

        float d2min[4] = {3.4e38f, 3.4e38f, 3.4e38f, 3.4e38f};

        #pragma unroll 2
        for (int nt = 0; nt < 16; ++nt) {
            int c = nt * 16 + row;
            unsigned co = (unsigned)c * 128u;
            unsigned sw = (((unsigned)c & 7u) << 4);
            short8v b0 = *(short8v*)((char*)tml + (co + (((unsigned)grp * 16u) ^ sw)));
            short8v b1 = *(short8v*)((char*)tml + (co + ((((unsigned)grp + 4u) * 16u) ^ sw)));
            float4v acc = {0.f, 0.f, 0.f, 0.f};
            acc = __builtin_amdgcn_mfma_f32_16x16x32_bf16(af0, b0, acc, 0, 0, 0);
            acc = __builtin_amdgcn_mfma_f32_16x16x32_bf16(af1, b1, acc, 0, 0, 0);
            float2 kt = ktab_sh[c];
            #pragma unroll
            for (int r = 0; r < 4; ++r) {
                float d2 = (snr[r] - 2.0f * acc[r]) + kt.x;
                if (!(d2 > kt.y)) d2min[r] = fminf(d2min[r], d2);  // thr2=-1 => masked
            }
        }

        // min over the 16 cluster-lanes (xor 1,2,4,8)
        #pragma unroll
        for (int o = 1; o < 16; o <<= 1) {
            #pragma unroll
            for (int r = 0; r < 4; ++r) d2min[r] = fminf(d2min[r], __shfl_xor(d2min[r], o));
        }
        if (row == 0) {
            #pragma unroll
            for (int r = 0; r < 4; ++r) {
                int i = i0 + grp * 4 + r;
                if (i < n) {
                    float dm = d2min[r];
                    out[2 * (size_t)n + i] = (dm > 1e37f) ? BIGF : sqrtf(fmaxf(dm, 0.f));
                }
            }
        }
    }

    // pass-through outputs + unmatched list (256 threads cover this block's 256 spikes)
    int i = blockIdx.x * 256 + threadIdx.x;
    if (i < n) {
        int si = sidx[i];
        out[i]             = (float)si;
        out[(size_t)n + i] = midx[i] ? 1.0f : 0.0f;
        if (si == 0) {
            int p = atomicAdd(&g_nlist, 1);
            if (p < 1000000) g_list[p] = i;
        }
    }
}

// ---------------- D: precise f64 argmin, LANE = CLUSTER ----------------
__global__ __launch_bounds__(256) void kprecise(const float* __restrict__ spikes,
                                                float* __restrict__ out, int n) {
    const int lane  = threadIdx.x & 63;
    const int gwave = (blockIdx.x * 256 + threadIdx.x) >> 6;
    const int nwave = (gridDim.x * 256) >> 6;
    const int nt    = g_nlist;

    // per-lane cluster constants (c = q*64 + lane), coalesced loads
    double tn[4], thr[4]; int vld[4];
    #pragma unroll
    for (int q = 0; q < 4; ++q) {
        int c = q * 64 + lane;
        tn[q]  = g_tn64[c];
        thr[q] = 1.5 * g_std64[c];
        vld[q] = g_valid[c];
    }

    for (int t = gwave; t < nt; t += nwave) {
        const int i = g_list[t];
        const double sf = (double)spikes[(size_t)i * NFEAT + lane];

        double sn = sf * sf;                 // once per spike
        #pragma unroll
        for (int o = 32; o; o >>= 1) sn += __shfl_xor(sn, o);

        double d0 = 0.0, d1 = 0.0, d2a = 0.0, d3 = 0.0;
        #pragma unroll 16
        for (int f = 0; f < NFEAT; ++f) {
            double b = __shfl(sf, f);        // independent across f
            const double* mrow = &g_means64T[(size_t)f * NCLUST + lane];
            d0 = fma(b, mrow[0],   d0);
            d1 = fma(b, mrow[64],  d1);
            d2a = fma(b, mrow[128], d2a);
            d3 = fma(b, mrow[192], d3);
        }
        double dot[4] = {d0, d1, d2a, d3};

        double dmin = 1e30; int best = 0;
        #pragma unroll
        for (int q = 0; q < 4; ++q) {        // ascending q => ascending cluster id
            if (!vld[q]) continue;
            double d2 = (sn - 2.0 * dot[q]) + tn[q];
            double dist = sqrt(fmax(d2, 0.0));
            if (dist > thr[q]) continue;
            if (dist < dmin) { dmin = dist; best = q * 64 + lane + 1; }
        }

        // cross-lane argmin with first-index tie-break
        #pragma unroll
        for (int o = 32; o; o >>= 1) {
            double od = __shfl_xor(dmin, o);
            int    ob = __shfl_xor(best, o);
            if (od < dmin || (od == dmin && ob < best)) { dmin = od; best = ob; }
        }

        if (dmin >= 256.0) best = 0;   // FIRST_MATCH_MAX_DIST * N_SAMPLES

        if (lane == 0) {
            out[i]                 = (float)best;
            out[(size_t)n + i]     = (best != 0) ? 1.0f : 0.0f;
            out[2 * (size_t)n + i] = (float)dmin;
        }
    }
}

extern "C" void kernel_launch(void* const* d_in, const int* in_sizes, int n_in,
                              void* d_out, int out_size, void* d_ws, size_t ws_size,
                              hipStream_t stream) {
    const float*         spikes = (const float*)d_in[0];
    const int*           sidx   = (const int*)d_in[1];
    const unsigned char* midx   = (const unsigned char*)d_in[2];
    float*               out    = (float*)d_out;
    const int n = in_sizes[1];

    kstats<<<NBLK_A, 1024, 0, stream>>>(spikes, sidx, n);
    kfinal<<<NCLUST, 256, 0, stream>>>();
    kmedian<<<1, 256, 0, stream>>>();
    int nblk = (n + 255) / 256;
    kmatch<<<nblk, 256, 0, stream>>>(spikes, sidx, midx, out, n);
    kprecise<<<1024, 256, 0, stream>>>(spikes, out, n);
}

// Round 11
// 208.415 us; speedup vs baseline: 1.2699x; 1.0102x over previous
//
#include <hip/hip_runtime.h>

#define NCLUST 256      // clusters 1..256 (cluster 0 = CLID_UNMATCHED, excluded)
#define NFEAT  64
#define NBLK_A 256      // 1 block/CU
#define BIGF   1e30f

#define SUMSC  16777216.0f      // 2^24 (pow2 mul = exact exponent shift)
#define SSQSC  2097152.0f       // 2^21
#define INV_SUMSC (1.0 / 16777216.0)
#define INV_SSQSC (1.0 / 2097152.0)

typedef __attribute__((ext_vector_type(8))) short  short8v;   // 8 x bf16
typedef __attribute__((ext_vector_type(4))) float  float4v;
typedef unsigned long long u64;

// ---- static device scratch (rewritten fully every call) ----
// u32 fixed-point partials (FEATURE-PERMUTED: word (f&1)*32 + (f>>1) per cluster row)
__device__ __align__(16) unsigned g_psum[(size_t)NCLUST * NBLK_A * NFEAT]; // 16.7MB
__device__ __align__(16) unsigned g_pssq[(size_t)NCLUST * NBLK_A * NFEAT]; // 16.7MB
__device__ unsigned g_pcnt[NCLUST * NBLK_A * 8];
__device__ float  g_cnt[NCLUST];
__device__ __align__(16) double g_means64[NCLUST * NFEAT];
__device__ __align__(16) double g_means64T[NFEAT * NCLUST];   // transposed [f][c]
__device__ __align__(16) unsigned short g_tmplbf[NCLUST * NFEAT]; // swizzled bf16 templates
__device__ double g_tn64[NCLUST];
__device__ double g_std64[NCLUST];
__device__ float  g_std32[NCLUST];
__device__ float2 g_ktab[NCLUST];         // (tn_f32, thr2_f32 or -1 if invalid)
__device__ int    g_valid[NCLUST];
__device__ int    g_list[1000000];
__device__ int    g_nlist;

static __device__ __forceinline__ unsigned short f2bf(float x) {
    union { float f; unsigned u; } v; v.f = x;
    unsigned r = v.u + 0x7fffu + ((v.u >> 16) & 1u);   // RNE
    return (unsigned short)(r >> 16);
}

// ---------------- A: segment sums, u32 fire-and-forget LDS atomics ----------------
// R10 bank arithmetic: lane m hitting words {2m, 2m+1} = even-banks-only,
// 4-way conflict on every ds_add (1.58x, m136). Fix: permuted layout
// word(f) = (f&1)*32 + (f>>1) -> .x atomics hit banks 0..31 one lane each per
// half (2-way across halves = free), .y likewise. Also 32-spike batch: 16
// float2 in flight/wave = 64KB/CU >> 22KB BW-latency product -> HBM-roof.
__global__ __launch_bounds__(1024, 4) void kstats(const float* __restrict__ spikes,
                                                  const int* __restrict__ sidx, int n) {
    __shared__ unsigned lsum[NCLUST * NFEAT]; // 64 KiB  fixed-point 2^24 (permuted)
    __shared__ unsigned lssq[NCLUST * NFEAT]; // 64 KiB  fixed-point 2^21 (permuted)
    __shared__ unsigned lcnt[NCLUST * 8];     // 8 KiB
    for (int idx = threadIdx.x; idx < NCLUST * NFEAT; idx += 1024) { lsum[idx] = 0u; lssq[idx] = 0u; }
    for (int idx = threadIdx.x; idx < NCLUST * 8; idx += 1024) lcnt[idx] = 0u;
    __syncthreads();

    const int lane = threadIdx.x & 63;
    const int wave = threadIdx.x >> 6;          // 0..15
    const int half = lane >> 5;                 // 0/1: which spike of the pair
    const int m    = lane & 31;                 // feature pair index (feats 2m, 2m+1)
    const int per  = (n + gridDim.x - 1) / gridDim.x;
    const int s0   = blockIdx.x * per;
    const int s1   = min(n, s0 + per);

    for (int ib = s0 + wave * 32; ib < s1; ib += 16 * 32) {   // 16 pairs = 32 spikes/wave/iter
        float2 v[16]; int cc[16];
        #pragma unroll
        for (int p = 0; p < 16; ++p) {
            int i  = ib + p * 2 + half;
            int rc = (i < s1) ? i : (s1 - 1);
            v[p]  = *(const float2*)(spikes + (size_t)rc * NFEAT + m * 2);
            cc[p] = (i < s1) ? sidx[i] : 0;
        }
        #pragma unroll
        for (int p = 0; p < 16; ++p) {
            int c = cc[p];
            if (c != 0) {                        // per-half predication; atomics exec-masked
                int base = (c - 1) * NFEAT;
                atomicAdd(&lsum[base + m],      (unsigned)__float2int_rn(v[p].x * SUMSC));
                atomicAdd(&lsum[base + 32 + m], (unsigned)__float2int_rn(v[p].y * SUMSC));
                atomicAdd(&lssq[base + m],      (unsigned)__float2int_rn(v[p].x * v[p].x * SSQSC));
                atomicAdd(&lssq[base + 32 + m], (unsigned)__float2int_rn(v[p].y * v[p].y * SSQSC));
                if (m == 0) atomicAdd(&lcnt[(c - 1) * 8 + (wave & 7)], 1u);
            }
        }
    }
    __syncthreads();

    const int b = blockIdx.x;
    for (int idx = threadIdx.x; idx < NCLUST * NFEAT; idx += 1024) {
        int c = idx >> 6, w = idx & 63;
        g_psum[((size_t)c * NBLK_A + b) * NFEAT + w] = lsum[idx];   // stays permuted
        g_pssq[((size_t)c * NBLK_A + b) * NFEAT + w] = lssq[idx];
    }
    for (int idx = threadIdx.x; idx < NCLUST * 8; idx += 1024) {
        int c = idx >> 3, k = idx & 7;
        g_pcnt[(c * NBLK_A + b) * 8 + k] = lcnt[idx];
    }
}

// ---------------- A2: exact integer reduce -> f64 means / tn / std + bf16 templates ----------------
__global__ __launch_bounds__(256) void kfinal() {
    const int c = blockIdx.x;                 // cluster c+1
    __shared__ long long red [4][NFEAT];
    __shared__ long long redq[4][NFEAT];
    __shared__ double smean[NFEAT];
    __shared__ double sh_cnt;
    const int f = threadIdx.x & 63, j = threadIdx.x >> 6;
    const int w = ((f & 1) << 5) | (f >> 1);  // permuted word for feature f

    long long acc = 0, accq = 0;
    for (int b = j; b < NBLK_A; b += 4) {
        acc  += (int)g_psum[((size_t)c * NBLK_A + b) * NFEAT + w];   // same 256B segment/(c,b)
        accq += (int)g_pssq[((size_t)c * NBLK_A + b) * NFEAT + w];
    }
    red[j][f] = acc; redq[j][f] = accq;

    if (threadIdx.x < 64) {
        unsigned cn = 0u;
        for (int e = threadIdx.x; e < NBLK_A * 8; e += 64)
            cn += g_pcnt[c * NBLK_A * 8 + e];
        #pragma unroll
        for (int o = 32; o; o >>= 1) cn += __shfl_xor(cn, o);
        if (threadIdx.x == 0) sh_cnt = (double)cn;
    }
    __syncthreads();

    if (threadIdx.x < NFEAT) {
        long long tot = ((red[0][f] + red[1][f]) + red[2][f]) + red[3][f];
        double cnt = sh_cnt;
        double mean = (cnt > 0.0) ? ((double)tot * INV_SUMSC) / cnt : 0.0;
        g_means64[c * NFEAT + f]   = mean;
        g_means64T[f * NCLUST + c] = mean;
        smean[f] = mean;
        redq[0][f] = ((redq[0][f] + redq[1][f]) + redq[2][f]) + redq[3][f];
        // bf16 template write, swizzled layout
        unsigned short hb = f2bf((float)mean);
        unsigned g = (unsigned)(f >> 3);
        unsigned byteoff = (unsigned)c * 128u
                         + (((g * 16u) ^ (((unsigned)c & 7u) << 4)) + (unsigned)(f & 7) * 2u);
        *(unsigned short*)((char*)g_tmplbf + byteoff) = hb;
    }
    __syncthreads();
    if (threadIdx.x == 0) {
        double tn = 0.0; long long qs = 0;
        for (int q = 0; q < NFEAT; ++q) { tn += smean[q] * smean[q]; qs += redq[0][q]; }
        double cnt = sh_cnt;
        double var = (cnt > 0.0) ? ((double)qs * INV_SSQSC) / cnt - tn : 0.0;
        if (var < 0.0) var = 0.0;
        double sd = sqrt(var);
        g_tn64[c] = tn; g_std64[c] = sd; g_std32[c] = (float)sd;
        g_cnt[c] = (float)cnt;
    }
}

// ---------------- A3: median, validity, thresholds (tiny serial kernel) ----------------
__global__ __launch_bounds__(256) void kmedian() {
    __shared__ float svals[NCLUST];
    __shared__ int   svalid[NCLUST];
    __shared__ float mred[2];
    int t = threadIdx.x;
    if (t == 0) { mred[0] = 0.f; mred[1] = 0.f; g_nlist = 0; }
    float cnt = g_cnt[t];
    int v0 = (cnt > 0.f) ? 1 : 0;
    float sd = g_std32[t];
    svals[t] = sd; svalid[t] = v0;
    __syncthreads();

    int m = 0, rank = 0;
    for (int jj = 0; jj < NCLUST; ++jj) {
        if (svalid[jj]) {
            ++m;
            float sj = svals[jj];
            if (sj < sd || (sj == sd && jj < t)) ++rank;
        }
    }
    if (v0) {
        if (rank == (m - 1) / 2) mred[0] = sd;
        if (rank == m / 2)       mred[1] = sd;
    }
    __syncthreads();
    float med = 0.5f * (mred[0] + mred[1]);

    int valid = v0 && (sd <= 3.0f * med);
    double sd64 = g_std64[t];
    float thr2 = valid ? (float)((1.5 * sd64) * (1.5 * sd64)) : -1.0f;
    g_valid[t] = valid;
    g_ktab[t]  = make_float2((float)g_tn64[t], thr2);
}

// ---------------- C: MFMA bulk min pass, 256 spikes per block ----------------
// mfma_f32_16x16x32_bf16: A lane l -> row=l&15, k=(l>>4)*8+j ; B lane l -> col=l&15, same k map.
// D lane l, reg r -> row=(l>>4)*4+r, col=l&15  [verified layout, m89]
__global__ __launch_bounds__(256) void kmatch(const float* __restrict__ spikes,
                                              const int* __restrict__ sidx,
                                              const unsigned char* __restrict__ midx,
                                              float* __restrict__ out, int n) {
    __shared__ __align__(16) unsigned short tml[NCLUST * NFEAT]; // 32 KiB swizzled bf16
    __shared__ float2 ktab_sh[NCLUST];

    // stage pre-swizzled templates: linear 16B copies
    for (int idx = threadIdx.x * 8; idx < NCLUST * NFEAT; idx += 256 * 8)
        *(short8v*)&tml[idx] = *(const short8v*)&g_tmplbf[idx];
    if (threadIdx.x < NCLUST) ktab_sh[threadIdx.x] = g_ktab[threadIdx.x];
    __syncthreads();

    const int lane = threadIdx.x & 63, wave = threadIdx.x >> 6;
    const int row  = lane & 15, grp = lane >> 4;
    const int i0w  = blockIdx.x * 256 + wave * 64;   // this wave's 64 spikes

    #pragma unroll 1
    for (int sb = 0; sb < 4; ++sb) {
        const int i0 = i0w + sb * 16;

        // ---- A fragments (spikes straight from global, f32 -> bf16) ----
        int ri = i0 + row;
        int rc = (ri < n) ? ri : (n - 1);
        const float* sp = spikes + (size_t)rc * NFEAT + grp * 8;
        float4 a0 = *(const float4*)(sp);
        float4 a1 = *(const float4*)(sp + 4);
        float4 a2 = *(const float4*)(sp + 32);
        float4 a3 = *(const float4*)(sp + 36);
        short8v af0, af1;
        af0[0] = (short)f2bf(a0.x); af0[1] = (short)f2bf(a0.y);
        af0[2] = (short)f2bf(a0.z); af0[3] = (short)f2bf(a0.w);
        af0[4] = (short)f2bf(a1.x); af0[5] = (short)f2bf(a1.y);
        af0[6] = (short)f2bf(a1.z); af0[7] = (short)f2bf(a1.w);
        af1[0] = (short)f2bf(a2.x); af1[1] = (short)f2bf(a2.y);
        af1[2] = (short)f2bf(a2.z); af1[3] = (short)f2bf(a2.w);
        af1[4] = (short)f2bf(a3.x); af1[5] = (short)f2bf(a3.y);
        af1[6] = (short)f2bf(a3.z); af1[7] = (short)f2bf(a3.w);

        // sn (|s|^2) in f32 from ORIGINAL f32 values; reduce across the 4 k-groups
        float pss = a0.x*a0.x + a0.y*a0.y + a0.z*a0.z + a0.w*a0.w
                  + a1.x*a1.x + a1.y*a1.y + a1.z*a1.z + a1.w*a1.w
                  + a2.x*a2.x + a2.y*a2.y + a2.z*a2.z + a2.w*a2.w
                  + a3.x*a3.x + a3.y*a3.y + a3.z*a3.z + a3.w*a3.w;
        pss += __shfl_xor(pss, 16);
        pss += __shfl_xor(pss, 32);          // now sn of row `row` on every lane

        float snr[4];
        #pragma unroll
        for (int r = 0; r < 4; ++r) snr[r] = __shfl(pss, grp * 4 + r);

        float d2min[4] = {3.4e38f, 3.4e38f, 3.4e38f, 3.4e38f};

        #pragma unroll 2
        for (int nt = 0; nt < 16; ++nt) {
            int c = nt * 16 + row;
            unsigned co = (unsigned)c * 128u;
            unsigned sw = (((unsigned)c & 7u) << 4);
            short8v b0 = *(short8v*)((char*)tml + (co + (((unsigned)grp * 16u) ^ sw)));
            short8v b1 = *(short8v*)((char*)tml + (co + ((((unsigned)grp + 4u) * 16u) ^ sw)));
            float4v acc = {0.f, 0.f, 0.f, 0.f};
            acc = __builtin_amdgcn_mfma_f32_16x16x32_bf16(af0, b0, acc, 0, 0, 0);
            acc = __builtin_amdgcn_mfma_f32_16x16x32_bf16(af1, b1, acc, 0, 0, 0);
            float2 kt = ktab_sh[c];
            #pragma unroll
            for (int r = 0; r < 4; ++r) {
                float d2 = (snr[r] - 2.0f * acc[r]) + kt.x;
                if (!(d2 > kt.y)) d2min[r] = fminf(d2min[r], d2);  // thr2=-1 => masked
            }
        }

        // min over the 16 cluster-lanes (xor 1,2,4,8)
        #pragma unroll
        for (int o = 1; o < 16; o <<= 1) {
            #pragma unroll
            for (int r = 0; r < 4; ++r) d2min[r] = fminf(d2min[r], __shfl_xor(d2min[r], o));
        }
        if (row == 0) {
            #pragma unroll
            for (int r = 0; r < 4; ++r) {
                int i = i0 + grp * 4 + r;
                if (i < n) {
                    float dm = d2min[r];
                    out[2 * (size_t)n + i] = (dm > 1e37f) ? BIGF : sqrtf(fmaxf(dm, 0.f));
                }
            }
        }
    }

    // pass-through outputs + unmatched list (256 threads cover this block's 256 spikes)
    int i = blockIdx.x * 256 + threadIdx.x;
    if (i < n) {
        int si = sidx[i];
        out[i]             = (float)si;
        out[(size_t)n + i] = midx[i] ? 1.0f : 0.0f;
        if (si == 0) {
            int p = atomicAdd(&g_nlist, 1);
            if (p < 1000000) g_list[p] = i;
        }
    }
}

// ---------------- D: precise f64 argmin, LANE = CLUSTER ----------------
__global__ __launch_bounds__(256) void kprecise(const float* __restrict__ spikes,
                                                float* __restrict__ out, int n) {
    const int lane  = threadIdx.x & 63;
    const int gwave = (blockIdx.x * 256 + threadIdx.x) >> 6;
    const int nwave = (gridDim.x * 256) >> 6;
    const int nt    = g_nlist;

    // per-lane cluster constants (c = q*64 + lane), coalesced loads
    double tn[4], thr[4]; int vld[4];
    #pragma unroll
    for (int q = 0; q < 4; ++q) {
        int c = q * 64 + lane;
        tn[q]  = g_tn64[c];
        thr[q] = 1.5 * g_std64[c];
        vld[q] = g_valid[c];
    }

    for (int t = gwave; t < nt; t += nwave) {
        const int i = g_list[t];
        const double sf = (double)spikes[(size_t)i * NFEAT + lane];

        double sn = sf * sf;                 // once per spike
        #pragma unroll
        for (int o = 32; o; o >>= 1) sn += __shfl_xor(sn, o);

        double d0 = 0.0, d1 = 0.0, d2a = 0.0, d3 = 0.0;
        #pragma unroll 16
        for (int f = 0; f < NFEAT; ++f) {
            double b = __shfl(sf, f);        // independent across f
            const double* mrow = &g_means64T[(size_t)f * NCLUST + lane];
            d0 = fma(b, mrow[0],   d0);
            d1 = fma(b, mrow[64],  d1);
            d2a = fma(b, mrow[128], d2a);
            d3 = fma(b, mrow[192], d3);
        }
        double dot[4] = {d0, d1, d2a, d3};

        double dmin = 1e30; int best = 0;
        #pragma unroll
        for (int q = 0; q < 4; ++q) {        // ascending q => ascending cluster id
            if (!vld[q]) continue;
            double d2 = (sn - 2.0 * dot[q]) + tn[q];
            double dist = sqrt(fmax(d2, 0.0));
            if (dist > thr[q]) continue;
            if (dist < dmin) { dmin = dist; best = q * 64 + lane + 1; }
        }

        // cross-lane argmin with first-index tie-break
        #pragma unroll
        for (int o = 32; o; o >>= 1) {
            double od = __shfl_xor(dmin, o);
            int    ob = __shfl_xor(best, o);
            if (od < dmin || (od == dmin && ob < best)) { dmin = od; best = ob; }
        }

        if (dmin >= 256.0) best = 0;   // FIRST_MATCH_MAX_DIST * N_SAMPLES

        if (lane == 0) {
            out[i]                 = (float)best;
            out[(size_t)n + i]     = (best != 0) ? 1.0f : 0.0f;
            out[2 * (size_t)n + i] = (float)dmin;
        }
    }
}

extern "C" void kernel_launch(void* const* d_in, const int* in_sizes, int n_in,
                              void* d_out, int out_size, void* d_ws, size_t ws_size,
                              hipStream_t stream) {
    const float*         spikes = (const float*)d_in[0];
    const int*           sidx   = (const int*)d_in[1];
    const unsigned char* midx   = (const unsigned char*)d_in[2];
    float*               out    = (float*)d_out;
    const int n = in_sizes[1];

    kstats<<<NBLK_A, 1024, 0, stream>>>(spikes, sidx, n);
    kfinal<<<NCLUST, 256, 0, stream>>>();
    kmedian<<<1, 256, 0, stream>>>();
    int nblk = (n + 255) / 256;
    kmatch<<<nblk, 256, 0, stream>>>(spikes, sidx, midx, out, n);
    kprecise<<<1024, 256, 0, stream>>>(spikes, out, n);
}